// Round 3
// baseline (214.479 us; speedup 1.0000x reference)
//
#include <hip/hip_runtime.h>
#include <cstdint>
#include <cstddef>

typedef __bf16 bf16;
typedef __attribute__((ext_vector_type(4))) __bf16 bf16x4;
typedef __attribute__((ext_vector_type(8))) __bf16 bf16x8;
typedef __attribute__((ext_vector_type(4))) float floatx4;
typedef __attribute__((ext_vector_type(4))) short short4v;

#define MFMA16(a, b, c) __builtin_amdgcn_mfma_f32_16x16x32_bf16((a), (b), (c), 0, 0, 0)

// K=16 bf16 MFMA: A[m=l16][k=quad*4+j], B[n=l16][k=quad*4+j], C row=quad*4+r col=l16
__device__ __forceinline__ floatx4 MFMAK16(bf16x4 a, bf16x4 b, floatx4 c) {
#if __has_builtin(__builtin_amdgcn_mfma_f32_16x16x16bf16_1k)
  return __builtin_amdgcn_mfma_f32_16x16x16bf16_1k(
      __builtin_bit_cast(short4v, a), __builtin_bit_cast(short4v, b), c, 0, 0, 0);
#else
  floatx4 d;
  asm("v_mfma_f32_16x16x16_bf16 %0, %1, %2, %3"
      : "=v"(d)
      : "v"(a), "v"(b), "v"(c));
  return d;
#endif
}

constexpr int DMODEL = 1024;
constexpr int NH = 16;
constexpr int DKH = 64;
constexpr int B_ = 2;
constexpr int S_ = 2048;
constexpr int MTOT = B_ * S_;  // 4096
constexpr float CEXP = 0.125f * 1.44269504f;  // log2(e)/sqrt(64), folded into Q

// async global->LDS, 16B/lane; LDS dest = wave-uniform base + lane*16
__device__ __forceinline__ void load_lds16(const void* g, void* l) {
  __builtin_amdgcn_global_load_lds(
      (const __attribute__((address_space(1))) uint32_t*)g,
      (__attribute__((address_space(3))) uint32_t*)l, 16, 0, 0);
}

// ---------------------------------------------------------------------------
// Swizzled LDS tiles: 64-col bf16 rows (8 x 16B chunks/row), chunk swizzle
// s = c ^ (row & 7); reads via frag64 (b128) / frag64h (b64) -> <=2-way banks.
// ---------------------------------------------------------------------------
__device__ __forceinline__ bf16x8 frag64(const bf16* lds, int row, int p) {
  int s = p ^ (row & 7);
  return *(const bf16x8*)&lds[row * 64 + s * 8];
}
// 8B read at global chunk p (16B units), sub-half h (0/1)
__device__ __forceinline__ bf16x4 frag64h(const bf16* lds, int row, int p, int h) {
  int s = p ^ (row & 7);
  return *(const bf16x4*)&lds[row * 64 + s * 8 + h * 4];
}

// 32-col variants (BK=32 fallback path)
__device__ __forceinline__ void stage32_bf16(const bf16* __restrict__ src,
                                             bf16* lds, int wave, int lane,
                                             int ldg) {
#pragma unroll
  for (int i = 0; i < 2; ++i) {
    int cb = (wave * 2 + i) * 64;
    int c = cb + lane;
    int r = c >> 2;
    int s = (c & 3) ^ ((r >> 1) & 3);
    load_lds16(&src[(size_t)r * ldg + s * 8], &lds[cb * 8]);
  }
}
__device__ __forceinline__ bf16x8 frag32_bf16(const bf16* lds, int row,
                                              int quad) {
  int s = quad ^ ((row >> 1) & 3);
  return *(const bf16x8*)&lds[row * 32 + s * 8];
}
__device__ __forceinline__ void stage32_f32(const float* __restrict__ src,
                                            float* lds, int wave, int lane,
                                            int ldg) {
#pragma unroll
  for (int i = 0; i < 4; ++i) {
    int cb = (wave * 4 + i) * 64;
    int c = cb + lane;
    int r = c >> 3;
    int s = (c & 7) ^ (r & 7);
    load_lds16(&src[(size_t)r * ldg + s * 4], &lds[cb * 4]);
  }
}
__device__ __forceinline__ bf16x8 frag32_f32(const float* lds, int row,
                                             int quad) {
  int s1 = (2 * quad) ^ (row & 7);
  int s2 = (2 * quad + 1) ^ (row & 7);
  float4 a = *(const float4*)&lds[row * 32 + s1 * 4];
  float4 b = *(const float4*)&lds[row * 32 + s2 * 4];
  bf16x8 h = {(bf16)a.x, (bf16)a.y, (bf16)a.z, (bf16)a.w,
              (bf16)b.x, (bf16)b.y, (bf16)b.z, (bf16)b.w};
  return h;
}

// ---------------------------------------------------------------------------
// fp32 -> bf16 bulk convert (fast path only). grid (2048, 7).
// ---------------------------------------------------------------------------
__global__ __launch_bounds__(256) void convert_kernel(
    const float* __restrict__ q, const float* __restrict__ k,
    const float* __restrict__ v, const float* __restrict__ wq,
    const float* __restrict__ wk, const float* __restrict__ wv,
    const float* __restrict__ wo, bf16* __restrict__ qb, bf16* __restrict__ kb,
    bf16* __restrict__ vb, bf16* __restrict__ wqb, bf16* __restrict__ wkb,
    bf16* __restrict__ wvb, bf16* __restrict__ wob) {
  const float* src;
  bf16* dst;
  size_t n;
  switch (blockIdx.y) {
    case 0: src = q;  dst = qb;  n = (size_t)MTOT * DMODEL; break;
    case 1: src = k;  dst = kb;  n = (size_t)MTOT * DMODEL; break;
    case 2: src = v;  dst = vb;  n = (size_t)MTOT * DMODEL; break;
    case 3: src = wq; dst = wqb; n = (size_t)DMODEL * DMODEL; break;
    case 4: src = wk; dst = wkb; n = (size_t)DMODEL * DMODEL; break;
    case 5: src = wv; dst = wvb; n = (size_t)DMODEL * DMODEL; break;
    default: src = wo; dst = wob; n = (size_t)DMODEL * DMODEL; break;
  }
  size_t idx = ((size_t)blockIdx.x * 256 + threadIdx.x) * 8;
  if (idx >= n) return;
  float4 f0 = *(const float4*)&src[idx];
  float4 f1 = *(const float4*)&src[idx + 4];
  bf16x8 h = {(bf16)f0.x, (bf16)f0.y, (bf16)f0.z, (bf16)f0.w,
              (bf16)f1.x, (bf16)f1.y, (bf16)f1.z, (bf16)f1.w};
  *(bf16x8*)&dst[idx] = h;
}

// ---------------------------------------------------------------------------
// gemm64: bf16 GEMM, 128x128 tile, BK=64, 4 waves. C-store scaled by ascale
// (used to fold the attention softmax scale into Q). vt: Vt scatter path.
// ---------------------------------------------------------------------------
template <typename TC>
__device__ __forceinline__ void gemm64(const bf16* __restrict__ A,
                                       const bf16* __restrict__ W,
                                       TC* __restrict__ C,
                                       bf16* __restrict__ vt, int K,
                                       int m0, int n0, float ascale) {
  constexpr int N = DMODEL;
  __shared__ alignas(16) bf16 As[128 * 64];
  __shared__ alignas(16) bf16 Bs[128 * 64];

  const int tid = threadIdx.x;
  const int wave = tid >> 6;
  const int lane = tid & 63;
  const int quad = lane >> 4;
  const int l16 = lane & 15;
  const int wm = (wave >> 1) * 64;
  const int wn = (wave & 1) * 64;

  floatx4 acc[4][4] = {};

  for (int k0 = 0; k0 < K; k0 += 64) {
#pragma unroll
    for (int i = 0; i < 4; ++i) {
      int cb = (wave * 4 + i) * 64;
      int c = cb + lane;
      int r = c >> 3;
      int s = (c & 7) ^ (r & 7);
      load_lds16(&A[(size_t)(m0 + r) * K + k0 + s * 8], &As[cb * 8]);
      load_lds16(&W[(size_t)(n0 + r) * K + k0 + s * 8], &Bs[cb * 8]);
    }
    __syncthreads();

#pragma unroll
    for (int kk = 0; kk < 2; ++kk) {
      bf16x8 af[4], bfv[4];
#pragma unroll
      for (int mi = 0; mi < 4; ++mi)
        af[mi] = frag64(As, wm + mi * 16 + l16, kk * 4 + quad);
#pragma unroll
      for (int ni = 0; ni < 4; ++ni)
        bfv[ni] = frag64(Bs, wn + ni * 16 + l16, kk * 4 + quad);
#pragma unroll
      for (int mi = 0; mi < 4; ++mi)
#pragma unroll
        for (int ni = 0; ni < 4; ++ni)
          acc[mi][ni] = MFMA16(af[mi], bfv[ni], acc[mi][ni]);
    }
    __syncthreads();
  }

  if (vt) {
#pragma unroll
    for (int mi = 0; mi < 4; ++mi)
#pragma unroll
      for (int ni = 0; ni < 4; ++ni)
#pragma unroll
        for (int r = 0; r < 4; ++r) {
          int row = m0 + wm + mi * 16 + quad * 4 + r;
          int col = n0 + wn + ni * 16 + l16;
          int bb = row >> 11, s = row & 2047;
          int h = col >> 6, d = col & 63;
          vt[(size_t)((bb * NH + h) * DKH + d) * S_ + s] = (bf16)acc[mi][ni][r];
        }
  } else {
#pragma unroll
    for (int mi = 0; mi < 4; ++mi)
#pragma unroll
      for (int ni = 0; ni < 4; ++ni)
#pragma unroll
        for (int r = 0; r < 4; ++r) {
          int row = m0 + wm + mi * 16 + quad * 4 + r;
          int col = n0 + wn + ni * 16 + l16;
          C[(size_t)row * N + col] = (TC)(acc[mi][ni][r] * ascale);
        }
  }
}

// qkv fast path: flat grid 768, XCD row-ownership (bid&7 = XCD round-robin).
__global__ __launch_bounds__(256, 3) void qkv64_kernel(
    const bf16* __restrict__ q, const bf16* __restrict__ k,
    const bf16* __restrict__ v, const bf16* __restrict__ wq,
    const bf16* __restrict__ wk, const bf16* __restrict__ wv,
    bf16* __restrict__ Q, bf16* __restrict__ K, bf16* __restrict__ Vt) {
  const int bid = blockIdx.x;
  const int xcd = bid & 7;
  const int j = bid >> 3;
  const int n = j & 7;
  const int rowslot = j >> 3;
  const int p = xcd * 12 + rowslot;
  const int z = p >> 5;
  const int y = p & 31;

  const bf16* A = (z == 0) ? q : (z == 1) ? k : v;
  const bf16* W = (z == 0) ? wq : (z == 1) ? wk : wv;
  bf16* C = (z == 0) ? Q : K;
  gemm64<bf16>(A, W, (z == 2) ? nullptr : C, (z == 2) ? Vt : nullptr,
               DMODEL, y * 128, n * 128, (z == 0) ? CEXP : 1.0f);
}

// oproj fast path: BM=64, BN=128, BK=64 -> grid 512 (2 blocks/CU), LDS 24KB.
__global__ __launch_bounds__(256) void oproj64_kernel(
    const bf16* __restrict__ A, const bf16* __restrict__ W,
    float* __restrict__ C) {
  constexpr int K = DMODEL;
  constexpr int N = DMODEL;
  __shared__ alignas(16) bf16 As[64 * 64];
  __shared__ alignas(16) bf16 Bs[128 * 64];

  const int bid = blockIdx.x;
  const int xcd = bid & 7;
  const int j = bid >> 3;
  const int n = j & 7;
  const int slot = j >> 3;
  const int mt = xcd * 8 + slot;
  const int m0 = mt * 64;
  const int n0 = n * 128;

  const int tid = threadIdx.x;
  const int wave = tid >> 6;
  const int lane = tid & 63;
  const int quad = lane >> 4;
  const int l16 = lane & 15;
  const int wm = (wave >> 1) * 32;
  const int wn = (wave & 1) * 64;

  floatx4 acc[2][4] = {};

  for (int k0 = 0; k0 < K; k0 += 64) {
#pragma unroll
    for (int i = 0; i < 2; ++i) {
      int cb = (wave * 2 + i) * 64;
      int c = cb + lane;
      int r = c >> 3;
      int s = (c & 7) ^ (r & 7);
      load_lds16(&A[(size_t)(m0 + r) * K + k0 + s * 8], &As[cb * 8]);
    }
#pragma unroll
    for (int i = 0; i < 4; ++i) {
      int cb = (wave * 4 + i) * 64;
      int c = cb + lane;
      int r = c >> 3;
      int s = (c & 7) ^ (r & 7);
      load_lds16(&W[(size_t)(n0 + r) * K + k0 + s * 8], &Bs[cb * 8]);
    }
    __syncthreads();

#pragma unroll
    for (int kk = 0; kk < 2; ++kk) {
      bf16x8 af[2], bfv[4];
#pragma unroll
      for (int mi = 0; mi < 2; ++mi)
        af[mi] = frag64(As, wm + mi * 16 + l16, kk * 4 + quad);
#pragma unroll
      for (int ni = 0; ni < 4; ++ni)
        bfv[ni] = frag64(Bs, wn + ni * 16 + l16, kk * 4 + quad);
#pragma unroll
      for (int mi = 0; mi < 2; ++mi)
#pragma unroll
        for (int ni = 0; ni < 4; ++ni)
          acc[mi][ni] = MFMA16(af[mi], bfv[ni], acc[mi][ni]);
    }
    __syncthreads();
  }

#pragma unroll
  for (int mi = 0; mi < 2; ++mi)
#pragma unroll
    for (int ni = 0; ni < 4; ++ni)
#pragma unroll
      for (int r = 0; r < 4; ++r) {
        int row = m0 + wm + mi * 16 + quad * 4 + r;
        int col = n0 + wn + ni * 16 + l16;
        C[(size_t)row * N + col] = acc[mi][ni][r];
      }
}

// ---------------------------------------------------------------------------
// Fallback (ws < 64MB): fp32-input GEMM, BK=32. ascale folds CEXP into Q.
// ---------------------------------------------------------------------------
template <typename TA, typename TW, typename TC>
__device__ __forceinline__ void gemm_core(const TA* __restrict__ A,
                                          const TW* __restrict__ W,
                                          TC* __restrict__ C,
                                          bf16* __restrict__ vt, int K,
                                          int m0, int n0, float ascale) {
  constexpr int N = DMODEL;
  __shared__ alignas(16) char smem[128 * 32 * (sizeof(TA) + sizeof(TW))];
  TA* As = (TA*)smem;
  TW* Bs = (TW*)(smem + 128 * 32 * sizeof(TA));

  const int tid = threadIdx.x;
  const int wave = tid >> 6;
  const int lane = tid & 63;
  const int quad = lane >> 4;
  const int l16 = lane & 15;
  const int wm = (wave >> 1) * 64;
  const int wn = (wave & 1) * 64;

  floatx4 acc[4][4] = {};

  for (int k0 = 0; k0 < K; k0 += 32) {
    if constexpr (sizeof(TA) == 2)
      stage32_bf16((const bf16*)A + (size_t)m0 * K + k0, (bf16*)As, wave, lane, K);
    else
      stage32_f32((const float*)A + (size_t)m0 * K + k0, (float*)As, wave, lane, K);
    if constexpr (sizeof(TW) == 2)
      stage32_bf16((const bf16*)W + (size_t)n0 * K + k0, (bf16*)Bs, wave, lane, K);
    else
      stage32_f32((const float*)W + (size_t)n0 * K + k0, (float*)Bs, wave, lane, K);
    __syncthreads();

    bf16x8 af[4], bfv[4];
#pragma unroll
    for (int mi = 0; mi < 4; ++mi) {
      if constexpr (sizeof(TA) == 2)
        af[mi] = frag32_bf16((const bf16*)As, wm + mi * 16 + l16, quad);
      else
        af[mi] = frag32_f32((const float*)As, wm + mi * 16 + l16, quad);
    }
#pragma unroll
    for (int ni = 0; ni < 4; ++ni) {
      if constexpr (sizeof(TW) == 2)
        bfv[ni] = frag32_bf16((const bf16*)Bs, wn + ni * 16 + l16, quad);
      else
        bfv[ni] = frag32_f32((const float*)Bs, wn + ni * 16 + l16, quad);
    }
#pragma unroll
    for (int mi = 0; mi < 4; ++mi)
#pragma unroll
      for (int ni = 0; ni < 4; ++ni)
        acc[mi][ni] = MFMA16(af[mi], bfv[ni], acc[mi][ni]);
    __syncthreads();
  }

  if (vt) {
#pragma unroll
    for (int mi = 0; mi < 4; ++mi)
#pragma unroll
      for (int ni = 0; ni < 4; ++ni)
#pragma unroll
        for (int r = 0; r < 4; ++r) {
          int row = m0 + wm + mi * 16 + quad * 4 + r;
          int col = n0 + wn + ni * 16 + l16;
          int bb = row >> 11, s = row & 2047;
          int h = col >> 6, d = col & 63;
          vt[(size_t)((bb * NH + h) * DKH + d) * S_ + s] = (bf16)acc[mi][ni][r];
        }
  } else {
#pragma unroll
    for (int mi = 0; mi < 4; ++mi)
#pragma unroll
      for (int ni = 0; ni < 4; ++ni)
#pragma unroll
        for (int r = 0; r < 4; ++r) {
          int row = m0 + wm + mi * 16 + quad * 4 + r;
          int col = n0 + wn + ni * 16 + l16;
          C[(size_t)row * N + col] = (TC)(acc[mi][ni][r] * ascale);
        }
  }
}

__global__ __launch_bounds__(256) void qkv_f32_kernel(
    const float* __restrict__ q, const float* __restrict__ k,
    const float* __restrict__ v, const float* __restrict__ wq,
    const float* __restrict__ wk, const float* __restrict__ wv,
    bf16* __restrict__ Q, bf16* __restrict__ K, bf16* __restrict__ Vt) {
  const int bid = blockIdx.x;
  const int xcd = bid & 7;
  const int j = bid >> 3;
  const int n = j & 7;
  const int rowslot = j >> 3;
  const int p = xcd * 12 + rowslot;
  const int z = p >> 5;
  const int y = p & 31;
  const float* A = (z == 0) ? q : (z == 1) ? k : v;
  const float* W = (z == 0) ? wq : (z == 1) ? wk : wv;
  bf16* C = (z == 0) ? Q : K;
  gemm_core<float, float, bf16>(A, W, (z == 2) ? nullptr : C,
                                (z == 2) ? Vt : nullptr, DMODEL, y * 128,
                                n * 128, (z == 0) ? CEXP : 1.0f);
}

__global__ __launch_bounds__(256) void oproj_f32_kernel(
    const bf16* __restrict__ A, const float* __restrict__ W,
    float* __restrict__ C) {
  const int bid = blockIdx.x;
  const int xcd = bid & 7;
  const int j = bid >> 3;
  const int n = j & 7;
  const int rowslot = j >> 3;
  const int y = xcd * 4 + rowslot;
  gemm_core<bf16, float, float>(A, W, C, nullptr, DMODEL, y * 128, n * 128,
                                1.0f);
}

// ---------------------------------------------------------------------------
// Causal flash attention v9: halve LDS-read bytes per query. 512 blocks x
// 128 threads (2 waves). Wave = 32-query half (qh) of BOTH paired q-tiles
// (pr, 31-pr): one ka/va register set (16 KB of LDS reads) now serves 64
// queries (v8: 32) -> per-CU LDS-read pipe demand halves (~44k -> ~22k cy,
// the largest pipe slice at the 43.5us plateau). 4 independent compute
// chains (2 tiles x 2 q-groups) give in-wave ILP at 1 wave/SIMD.
// ~230 VGPR -> __launch_bounds__(128,1). LDS 32.8 KB dbuf, 2 blocks/CU.
// ---------------------------------------------------------------------------
__device__ __forceinline__ void stage_kv2(const bf16* __restrict__ K,
                                          const bf16* __restrict__ Vt,
                                          bf16* Ks, bf16* Vts, size_t baseQ,
                                          size_t baseV, int kt, int wave,
                                          int lane) {
#pragma unroll
  for (int i = 0; i < 4; ++i) {
    int cb = (wave * 4 + i) * 64;
    int c = cb + lane;
    int r = c >> 3;
    int s = (c & 7) ^ (r & 7);
    load_lds16(&K[baseQ + (size_t)(kt * 64 + r) * DMODEL + s * 8], &Ks[cb * 8]);
    load_lds16(&Vt[baseV + (size_t)r * S_ + kt * 64 + s * 8], &Vts[cb * 8]);
  }
}

// one 64key x 32q tile (2 q-groups) from pre-loaded ka/va register fragments
template <bool DIAG>
__device__ __forceinline__ void tile32(const bf16x8 (&ka)[2][4],
                                       const bf16x4 (&va)[4][4],
                                       const bf16x8 (&qf)[2][2],
                                       floatx4 (&ot)[2][4], float (&lp)[2][4],
                                       int quad, int l16, int qh) {
#pragma unroll
  for (int qg = 0; qg < 2; ++qg) {
    // S^T = K Q^T : sa[kg] covers keys kg*16+quad*4+r, query l16
    floatx4 sa[4] = {};
#pragma unroll
    for (int kk = 0; kk < 2; ++kk)
#pragma unroll
      for (int kg = 0; kg < 4; ++kg)
        sa[kg] = MFMA16(ka[kk][kg], qf[qg][kk], sa[kg]);

    const int qb = qh * 32 + qg * 16 + l16;  // q index within the 64-row tile
    bf16x4 pb[4];
#pragma unroll
    for (int kg = 0; kg < 4; ++kg) {
      float pv[4];
#pragma unroll
      for (int r = 0; r < 4; ++r) {
        float s = sa[kg][r];
        if (DIAG) {
          int key = kg * 16 + quad * 4 + r;
          s = (key > qb) ? -3.0e38f : s;
        }
        float p = __builtin_amdgcn_exp2f(s);
        lp[qg][kg] += p;
        pv[r] = p;
      }
      pb[kg] = bf16x4{(bf16)pv[0], (bf16)pv[1], (bf16)pv[2], (bf16)pv[3]};
    }

    // O^T += V^T P^T (register-chained P)
#pragma unroll
    for (int kg = 0; kg < 4; ++kg)
#pragma unroll
      for (int di = 0; di < 4; ++di)
        ot[qg][di] = MFMAK16(va[kg][di], pb[kg], ot[qg][di]);
  }
}

__global__ __launch_bounds__(128, 1) void attn9_kernel(const bf16* __restrict__ Q,
                                                       const bf16* __restrict__ K,
                                                       const bf16* __restrict__ Vt,
                                                       bf16* __restrict__ O) {
  __shared__ alignas(16) bf16 Ks[2][64 * 64];
  __shared__ alignas(16) bf16 Vts[2][64 * 64];

  const int tid = threadIdx.x;
  const int wave = tid >> 6;  // q-half within both tiles
  const int lane = tid & 63;
  const int quad = lane >> 4;
  const int l16 = lane & 15;
  const int qh = wave;

  const int j = blockIdx.x;
  const int bh = j & 31;   // bid&7 = bh&7: heads spread across XCDs, K/V L2-resident
  const int pr = j >> 5;   // 0..15: pair (pr, 31-pr) -> constant 33 units/block
  const int qtL = pr;
  const int qtH = 31 - pr;
  const int h = bh & 15;
  const int b = bh >> 4;
  const size_t baseQ = (size_t)b * S_ * DMODEL + (size_t)h * DKH;
  const size_t baseV = (size_t)bh * DKH * S_;

  // Q fragments in B-operand layout (lane=q, k=quad*8+j), pre-scaled by CEXP.
  // qf[tile][qg][kk]
  bf16x8 qf[2][2][2];
#pragma unroll
  for (int t = 0; t < 2; ++t) {
    const int qt = t ? qtH : qtL;
#pragma unroll
    for (int qg = 0; qg < 2; ++qg)
#pragma unroll
      for (int kk = 0; kk < 2; ++kk)
        qf[t][qg][kk] = *(const bf16x8*)&Q[baseQ +
            (size_t)(qt * 64 + qh * 32 + qg * 16 + l16) * DMODEL + kk * 32 +
            quad * 8];
  }

  floatx4 ot[2][2][4] = {};  // [tile][qg][di]: O^T (d=di*16+quad*4+r, q=l16)
  float lp[2][2][4] = {};    // per-lane partial l
  
  stage_kv2(K, Vt, Ks[0], Vts[0], baseQ, baseV, 0, wave, lane);
  __syncthreads();  // drains vmcnt(0)

  for (int kt = 0; kt < qtH; ++kt) {
    const int cur = kt & 1;
    // issue next tile's staging first: latency hides under compute
    stage_kv2(K, Vt, Ks[cur ^ 1], Vts[cur ^ 1], baseQ, baseV, kt + 1, wave, lane);

    __builtin_amdgcn_s_setprio(1);
    // one fragment load serves both tiles and both q-groups (4 B per q*key)
    bf16x8 ka[2][4];
    bf16x4 va[4][4];
#pragma unroll
    for (int kk = 0; kk < 2; ++kk)
#pragma unroll
      for (int kg = 0; kg < 4; ++kg)
        ka[kk][kg] = frag64(Ks[cur], kg * 16 + l16, kk * 4 + quad);
#pragma unroll
    for (int kg = 0; kg < 4; ++kg)
#pragma unroll
      for (int di = 0; di < 4; ++di)
        va[kg][di] = frag64h(Vts[cur], di * 16 + l16, kg * 2 + (quad >> 1), quad & 1);

    if (kt < qtL) {
      tile32<false>(ka, va, qf[0], ot[0], lp[0], quad, l16, qh);
      tile32<false>(ka, va, qf[1], ot[1], lp[1], quad, l16, qh);
    } else if (kt == qtL) {
      tile32<true>(ka, va, qf[0], ot[0], lp[0], quad, l16, qh);
      tile32<false>(ka, va, qf[1], ot[1], lp[1], quad, l16, qh);
    } else {
      tile32<false>(ka, va, qf[1], ot[1], lp[1], quad, l16, qh);
    }
    __builtin_amdgcn_s_setprio(0);

    __syncthreads();  // vmcnt(0)+lgkmcnt(0) drain: next buffer ready
  }
  {  // last tile: diagonal of the high q-tile (qtL < qtH always since pr<16)
    const int cur = qtH & 1;
    bf16x8 ka[2][4];
    bf16x4 va[4][4];
#pragma unroll
    for (int kk = 0; kk < 2; ++kk)
#pragma unroll
      for (int kg = 0; kg < 4; ++kg)
        ka[kk][kg] = frag64(Ks[cur], kg * 16 + l16, kk * 4 + quad);
#pragma unroll
    for (int kg = 0; kg < 4; ++kg)
#pragma unroll
      for (int di = 0; di < 4; ++di)
        va[kg][di] = frag64h(Vts[cur], di * 16 + l16, kg * 2 + (quad >> 1), quad & 1);
    tile32<true>(ka, va, qf[1], ot[1], lp[1], quad, l16, qh);
  }

  // l: per-lane sum, reduce across the 4 quads sharing q=l16; store O^T->O
#pragma unroll
  for (int t = 0; t < 2; ++t) {
    const int qt = t ? qtH : qtL;
#pragma unroll
    for (int qg = 0; qg < 2; ++qg) {
      float l = (lp[t][qg][0] + lp[t][qg][1]) + (lp[t][qg][2] + lp[t][qg][3]);
      l += __shfl_xor(l, 16, 64);
      l += __shfl_xor(l, 32, 64);
      const float inv = 1.0f / l;
      const size_t orow = baseQ +
          (size_t)(qt * 64 + qh * 32 + qg * 16 + l16) * DMODEL;
#pragma unroll
      for (int di = 0; di < 4; ++di)
#pragma unroll
        for (int r = 0; r < 4; ++r)
          O[orow + di * 16 + quad * 4 + r] = (bf16)(ot[t][qg][di][r] * inv);
    }
  }
}

// ---------------------------------------------------------------------------
extern "C" void kernel_launch(void* const* d_in, const int* in_sizes, int n_in,
                              void* d_out, int out_size, void* d_ws,
                              size_t ws_size, hipStream_t stream) {
  const float* q = (const float*)d_in[0];
  const float* k = (const float*)d_in[1];
  const float* v = (const float*)d_in[2];
  // d_in[3] = causal mask: static tril, computed analytically in-kernel
  const float* wq = (const float*)d_in[4];
  const float* wk = (const float*)d_in[5];
  const float* wv = (const float*)d_in[6];
  const float* wo = (const float*)d_in[7];
  float* out = (float*)d_out;

  const size_t MB = 1024 * 1024;
  char* base = (char*)d_ws;
  bf16* Qp = (bf16*)(base);
  bf16* Kp = (bf16*)(base + 8 * MB);
  bf16* VtG = (bf16*)(base + 16 * MB);
  bf16* AO = (bf16*)(base + 24 * MB);

  if (ws_size >= 64 * MB) {
    bf16* qb = (bf16*)(base + 32 * MB);
    bf16* kb = (bf16*)(base + 40 * MB);
    bf16* vb = (bf16*)(base + 48 * MB);
    bf16* wqb = (bf16*)(base + 56 * MB);
    bf16* wkb = (bf16*)(base + 58 * MB);
    bf16* wvb = (bf16*)(base + 60 * MB);
    bf16* wob = (bf16*)(base + 62 * MB);
    convert_kernel<<<dim3(2048, 7), 256, 0, stream>>>(
        q, k, v, wq, wk, wv, wo, qb, kb, vb, wqb, wkb, wvb, wob);
    qkv64_kernel<<<dim3(768), 256, 0, stream>>>(
        qb, kb, vb, wqb, wkb, wvb, Qp, Kp, VtG);
    attn9_kernel<<<dim3(512), 128, 0, stream>>>(Qp, Kp, VtG, AO);
    oproj64_kernel<<<dim3(512), 256, 0, stream>>>(AO, wob, out);
  } else {
    qkv_f32_kernel<<<dim3(768), 256, 0, stream>>>(
        q, k, v, wq, wk, wv, Qp, Kp, VtG);
    attn9_kernel<<<dim3(512), 128, 0, stream>>>(Qp, Kp, VtG, AO);
    oproj_f32_kernel<<<dim3(256), 256, 0, stream>>>(AO, wo, out);
  }
}

// Round 4
// 203.428 us; speedup vs baseline: 1.0543x; 1.0543x over previous
//
#include <hip/hip_runtime.h>
#include <cstdint>
#include <cstddef>

typedef __bf16 bf16;
typedef __attribute__((ext_vector_type(4))) __bf16 bf16x4;
typedef __attribute__((ext_vector_type(8))) __bf16 bf16x8;
typedef __attribute__((ext_vector_type(4))) float floatx4;
typedef __attribute__((ext_vector_type(4))) short short4v;

#define MFMA16(a, b, c) __builtin_amdgcn_mfma_f32_16x16x32_bf16((a), (b), (c), 0, 0, 0)

// K=16 bf16 MFMA: A[m=l16][k=quad*4+j], B[n=l16][k=quad*4+j], C row=quad*4+r col=l16
__device__ __forceinline__ floatx4 MFMAK16(bf16x4 a, bf16x4 b, floatx4 c) {
#if __has_builtin(__builtin_amdgcn_mfma_f32_16x16x16bf16_1k)
  return __builtin_amdgcn_mfma_f32_16x16x16bf16_1k(
      __builtin_bit_cast(short4v, a), __builtin_bit_cast(short4v, b), c, 0, 0, 0);
#else
  floatx4 d;
  asm("v_mfma_f32_16x16x16_bf16 %0, %1, %2, %3"
      : "=v"(d)
      : "v"(a), "v"(b), "v"(c));
  return d;
#endif
}

constexpr int DMODEL = 1024;
constexpr int NH = 16;
constexpr int DKH = 64;
constexpr int B_ = 2;
constexpr int S_ = 2048;
constexpr int MTOT = B_ * S_;  // 4096
constexpr float CEXP = 0.125f * 1.44269504f;  // log2(e)/sqrt(64), folded into Q

// async global->LDS, 16B/lane; LDS dest = wave-uniform base + lane*16
__device__ __forceinline__ void load_lds16(const void* g, void* l) {
  __builtin_amdgcn_global_load_lds(
      (const __attribute__((address_space(1))) uint32_t*)g,
      (__attribute__((address_space(3))) uint32_t*)l, 16, 0, 0);
}

// ---------------------------------------------------------------------------
// Swizzled LDS tiles: 64-col bf16 rows (8 x 16B chunks/row), chunk swizzle
// s = c ^ (row & 7); reads via frag64 (b128) / frag64h (b64) -> <=2-way banks.
// ---------------------------------------------------------------------------
__device__ __forceinline__ bf16x8 frag64(const bf16* lds, int row, int p) {
  int s = p ^ (row & 7);
  return *(const bf16x8*)&lds[row * 64 + s * 8];
}
// 8B read at global chunk p (16B units), sub-half h (0/1)
__device__ __forceinline__ bf16x4 frag64h(const bf16* lds, int row, int p, int h) {
  int s = p ^ (row & 7);
  return *(const bf16x4*)&lds[row * 64 + s * 8 + h * 4];
}

// 32-col variants (BK=32 fallback path)
__device__ __forceinline__ void stage32_bf16(const bf16* __restrict__ src,
                                             bf16* lds, int wave, int lane,
                                             int ldg) {
#pragma unroll
  for (int i = 0; i < 2; ++i) {
    int cb = (wave * 2 + i) * 64;
    int c = cb + lane;
    int r = c >> 2;
    int s = (c & 3) ^ ((r >> 1) & 3);
    load_lds16(&src[(size_t)r * ldg + s * 8], &lds[cb * 8]);
  }
}
__device__ __forceinline__ bf16x8 frag32_bf16(const bf16* lds, int row,
                                              int quad) {
  int s = quad ^ ((row >> 1) & 3);
  return *(const bf16x8*)&lds[row * 32 + s * 8];
}
__device__ __forceinline__ void stage32_f32(const float* __restrict__ src,
                                            float* lds, int wave, int lane,
                                            int ldg) {
#pragma unroll
  for (int i = 0; i < 4; ++i) {
    int cb = (wave * 4 + i) * 64;
    int c = cb + lane;
    int r = c >> 3;
    int s = (c & 7) ^ (r & 7);
    load_lds16(&src[(size_t)r * ldg + s * 4], &lds[cb * 4]);
  }
}
__device__ __forceinline__ bf16x8 frag32_f32(const float* lds, int row,
                                             int quad) {
  int s1 = (2 * quad) ^ (row & 7);
  int s2 = (2 * quad + 1) ^ (row & 7);
  float4 a = *(const float4*)&lds[row * 32 + s1 * 4];
  float4 b = *(const float4*)&lds[row * 32 + s2 * 4];
  bf16x8 h = {(bf16)a.x, (bf16)a.y, (bf16)a.z, (bf16)a.w,
              (bf16)b.x, (bf16)b.y, (bf16)b.z, (bf16)b.w};
  return h;
}

// ---------------------------------------------------------------------------
// fp32 -> bf16 bulk convert (fast path only). grid (2048, 7).
// ---------------------------------------------------------------------------
__global__ __launch_bounds__(256) void convert_kernel(
    const float* __restrict__ q, const float* __restrict__ k,
    const float* __restrict__ v, const float* __restrict__ wq,
    const float* __restrict__ wk, const float* __restrict__ wv,
    const float* __restrict__ wo, bf16* __restrict__ qb, bf16* __restrict__ kb,
    bf16* __restrict__ vb, bf16* __restrict__ wqb, bf16* __restrict__ wkb,
    bf16* __restrict__ wvb, bf16* __restrict__ wob) {
  const float* src;
  bf16* dst;
  size_t n;
  switch (blockIdx.y) {
    case 0: src = q;  dst = qb;  n = (size_t)MTOT * DMODEL; break;
    case 1: src = k;  dst = kb;  n = (size_t)MTOT * DMODEL; break;
    case 2: src = v;  dst = vb;  n = (size_t)MTOT * DMODEL; break;
    case 3: src = wq; dst = wqb; n = (size_t)DMODEL * DMODEL; break;
    case 4: src = wk; dst = wkb; n = (size_t)DMODEL * DMODEL; break;
    case 5: src = wv; dst = wvb; n = (size_t)DMODEL * DMODEL; break;
    default: src = wo; dst = wob; n = (size_t)DMODEL * DMODEL; break;
  }
  size_t idx = ((size_t)blockIdx.x * 256 + threadIdx.x) * 8;
  if (idx >= n) return;
  float4 f0 = *(const float4*)&src[idx];
  float4 f1 = *(const float4*)&src[idx + 4];
  bf16x8 h = {(bf16)f0.x, (bf16)f0.y, (bf16)f0.z, (bf16)f0.w,
              (bf16)f1.x, (bf16)f1.y, (bf16)f1.z, (bf16)f1.w};
  *(bf16x8*)&dst[idx] = h;
}

// ---------------------------------------------------------------------------
// gemm64: bf16 GEMM, 128x128 tile, BK=64, 4 waves. C-store scaled by ascale
// (used to fold the attention softmax scale into Q). vt: Vt scatter path.
// ---------------------------------------------------------------------------
template <typename TC>
__device__ __forceinline__ void gemm64(const bf16* __restrict__ A,
                                       const bf16* __restrict__ W,
                                       TC* __restrict__ C,
                                       bf16* __restrict__ vt, int K,
                                       int m0, int n0, float ascale) {
  constexpr int N = DMODEL;
  __shared__ alignas(16) bf16 As[128 * 64];
  __shared__ alignas(16) bf16 Bs[128 * 64];

  const int tid = threadIdx.x;
  const int wave = tid >> 6;
  const int lane = tid & 63;
  const int quad = lane >> 4;
  const int l16 = lane & 15;
  const int wm = (wave >> 1) * 64;
  const int wn = (wave & 1) * 64;

  floatx4 acc[4][4] = {};

  for (int k0 = 0; k0 < K; k0 += 64) {
#pragma unroll
    for (int i = 0; i < 4; ++i) {
      int cb = (wave * 4 + i) * 64;
      int c = cb + lane;
      int r = c >> 3;
      int s = (c & 7) ^ (r & 7);
      load_lds16(&A[(size_t)(m0 + r) * K + k0 + s * 8], &As[cb * 8]);
      load_lds16(&W[(size_t)(n0 + r) * K + k0 + s * 8], &Bs[cb * 8]);
    }
    __syncthreads();

#pragma unroll
    for (int kk = 0; kk < 2; ++kk) {
      bf16x8 af[4], bfv[4];
#pragma unroll
      for (int mi = 0; mi < 4; ++mi)
        af[mi] = frag64(As, wm + mi * 16 + l16, kk * 4 + quad);
#pragma unroll
      for (int ni = 0; ni < 4; ++ni)
        bfv[ni] = frag64(Bs, wn + ni * 16 + l16, kk * 4 + quad);
#pragma unroll
      for (int mi = 0; mi < 4; ++mi)
#pragma unroll
        for (int ni = 0; ni < 4; ++ni)
          acc[mi][ni] = MFMA16(af[mi], bfv[ni], acc[mi][ni]);
    }
    __syncthreads();
  }

  if (vt) {
#pragma unroll
    for (int mi = 0; mi < 4; ++mi)
#pragma unroll
      for (int ni = 0; ni < 4; ++ni)
#pragma unroll
        for (int r = 0; r < 4; ++r) {
          int row = m0 + wm + mi * 16 + quad * 4 + r;
          int col = n0 + wn + ni * 16 + l16;
          int bb = row >> 11, s = row & 2047;
          int h = col >> 6, d = col & 63;
          vt[(size_t)((bb * NH + h) * DKH + d) * S_ + s] = (bf16)acc[mi][ni][r];
        }
  } else {
#pragma unroll
    for (int mi = 0; mi < 4; ++mi)
#pragma unroll
      for (int ni = 0; ni < 4; ++ni)
#pragma unroll
        for (int r = 0; r < 4; ++r) {
          int row = m0 + wm + mi * 16 + quad * 4 + r;
          int col = n0 + wn + ni * 16 + l16;
          C[(size_t)row * N + col] = (TC)(acc[mi][ni][r] * ascale);
        }
  }
}

// qkv fast path: flat grid 768, XCD row-ownership (bid&7 = XCD round-robin).
__global__ __launch_bounds__(256, 3) void qkv64_kernel(
    const bf16* __restrict__ q, const bf16* __restrict__ k,
    const bf16* __restrict__ v, const bf16* __restrict__ wq,
    const bf16* __restrict__ wk, const bf16* __restrict__ wv,
    bf16* __restrict__ Q, bf16* __restrict__ K, bf16* __restrict__ Vt) {
  const int bid = blockIdx.x;
  const int xcd = bid & 7;
  const int j = bid >> 3;
  const int n = j & 7;
  const int rowslot = j >> 3;
  const int p = xcd * 12 + rowslot;
  const int z = p >> 5;
  const int y = p & 31;

  const bf16* A = (z == 0) ? q : (z == 1) ? k : v;
  const bf16* W = (z == 0) ? wq : (z == 1) ? wk : wv;
  bf16* C = (z == 0) ? Q : K;
  gemm64<bf16>(A, W, (z == 2) ? nullptr : C, (z == 2) ? Vt : nullptr,
               DMODEL, y * 128, n * 128, (z == 0) ? CEXP : 1.0f);
}

// oproj fast path: BM=64, BN=128, BK=64 -> grid 512 (2 blocks/CU), LDS 24KB.
__global__ __launch_bounds__(256) void oproj64_kernel(
    const bf16* __restrict__ A, const bf16* __restrict__ W,
    float* __restrict__ C) {
  constexpr int K = DMODEL;
  constexpr int N = DMODEL;
  __shared__ alignas(16) bf16 As[64 * 64];
  __shared__ alignas(16) bf16 Bs[128 * 64];

  const int bid = blockIdx.x;
  const int xcd = bid & 7;
  const int j = bid >> 3;
  const int n = j & 7;
  const int slot = j >> 3;
  const int mt = xcd * 8 + slot;
  const int m0 = mt * 64;
  const int n0 = n * 128;

  const int tid = threadIdx.x;
  const int wave = tid >> 6;
  const int lane = tid & 63;
  const int quad = lane >> 4;
  const int l16 = lane & 15;
  const int wm = (wave >> 1) * 32;
  const int wn = (wave & 1) * 64;

  floatx4 acc[2][4] = {};

  for (int k0 = 0; k0 < K; k0 += 64) {
#pragma unroll
    for (int i = 0; i < 2; ++i) {
      int cb = (wave * 2 + i) * 64;
      int c = cb + lane;
      int r = c >> 3;
      int s = (c & 7) ^ (r & 7);
      load_lds16(&A[(size_t)(m0 + r) * K + k0 + s * 8], &As[cb * 8]);
    }
#pragma unroll
    for (int i = 0; i < 4; ++i) {
      int cb = (wave * 4 + i) * 64;
      int c = cb + lane;
      int r = c >> 3;
      int s = (c & 7) ^ (r & 7);
      load_lds16(&W[(size_t)(n0 + r) * K + k0 + s * 8], &Bs[cb * 8]);
    }
    __syncthreads();

#pragma unroll
    for (int kk = 0; kk < 2; ++kk) {
      bf16x8 af[2], bfv[4];
#pragma unroll
      for (int mi = 0; mi < 2; ++mi)
        af[mi] = frag64(As, wm + mi * 16 + l16, kk * 4 + quad);
#pragma unroll
      for (int ni = 0; ni < 4; ++ni)
        bfv[ni] = frag64(Bs, wn + ni * 16 + l16, kk * 4 + quad);
#pragma unroll
      for (int mi = 0; mi < 2; ++mi)
#pragma unroll
        for (int ni = 0; ni < 4; ++ni)
          acc[mi][ni] = MFMA16(af[mi], bfv[ni], acc[mi][ni]);
    }
    __syncthreads();
  }

#pragma unroll
  for (int mi = 0; mi < 2; ++mi)
#pragma unroll
    for (int ni = 0; ni < 4; ++ni)
#pragma unroll
      for (int r = 0; r < 4; ++r) {
        int row = m0 + wm + mi * 16 + quad * 4 + r;
        int col = n0 + wn + ni * 16 + l16;
        C[(size_t)row * N + col] = acc[mi][ni][r];
      }
}

// ---------------------------------------------------------------------------
// Fallback (ws < 64MB): fp32-input GEMM, BK=32. ascale folds CEXP into Q.
// ---------------------------------------------------------------------------
template <typename TA, typename TW, typename TC>
__device__ __forceinline__ void gemm_core(const TA* __restrict__ A,
                                          const TW* __restrict__ W,
                                          TC* __restrict__ C,
                                          bf16* __restrict__ vt, int K,
                                          int m0, int n0, float ascale) {
  constexpr int N = DMODEL;
  __shared__ alignas(16) char smem[128 * 32 * (sizeof(TA) + sizeof(TW))];
  TA* As = (TA*)smem;
  TW* Bs = (TW*)(smem + 128 * 32 * sizeof(TA));

  const int tid = threadIdx.x;
  const int wave = tid >> 6;
  const int lane = tid & 63;
  const int quad = lane >> 4;
  const int l16 = lane & 15;
  const int wm = (wave >> 1) * 64;
  const int wn = (wave & 1) * 64;

  floatx4 acc[4][4] = {};

  for (int k0 = 0; k0 < K; k0 += 32) {
    if constexpr (sizeof(TA) == 2)
      stage32_bf16((const bf16*)A + (size_t)m0 * K + k0, (bf16*)As, wave, lane, K);
    else
      stage32_f32((const float*)A + (size_t)m0 * K + k0, (float*)As, wave, lane, K);
    if constexpr (sizeof(TW) == 2)
      stage32_bf16((const bf16*)W + (size_t)n0 * K + k0, (bf16*)Bs, wave, lane, K);
    else
      stage32_f32((const float*)W + (size_t)n0 * K + k0, (float*)Bs, wave, lane, K);
    __syncthreads();

    bf16x8 af[4], bfv[4];
#pragma unroll
    for (int mi = 0; mi < 4; ++mi) {
      if constexpr (sizeof(TA) == 2)
        af[mi] = frag32_bf16((const bf16*)As, wm + mi * 16 + l16, quad);
      else
        af[mi] = frag32_f32((const float*)As, wm + mi * 16 + l16, quad);
    }
#pragma unroll
    for (int ni = 0; ni < 4; ++ni) {
      if constexpr (sizeof(TW) == 2)
        bfv[ni] = frag32_bf16((const bf16*)Bs, wn + ni * 16 + l16, quad);
      else
        bfv[ni] = frag32_f32((const float*)Bs, wn + ni * 16 + l16, quad);
    }
#pragma unroll
    for (int mi = 0; mi < 4; ++mi)
#pragma unroll
      for (int ni = 0; ni < 4; ++ni)
        acc[mi][ni] = MFMA16(af[mi], bfv[ni], acc[mi][ni]);
    __syncthreads();
  }

  if (vt) {
#pragma unroll
    for (int mi = 0; mi < 4; ++mi)
#pragma unroll
      for (int ni = 0; ni < 4; ++ni)
#pragma unroll
        for (int r = 0; r < 4; ++r) {
          int row = m0 + wm + mi * 16 + quad * 4 + r;
          int col = n0 + wn + ni * 16 + l16;
          int bb = row >> 11, s = row & 2047;
          int h = col >> 6, d = col & 63;
          vt[(size_t)((bb * NH + h) * DKH + d) * S_ + s] = (bf16)acc[mi][ni][r];
        }
  } else {
#pragma unroll
    for (int mi = 0; mi < 4; ++mi)
#pragma unroll
      for (int ni = 0; ni < 4; ++ni)
#pragma unroll
        for (int r = 0; r < 4; ++r) {
          int row = m0 + wm + mi * 16 + quad * 4 + r;
          int col = n0 + wn + ni * 16 + l16;
          C[(size_t)row * N + col] = (TC)(acc[mi][ni][r] * ascale);
        }
  }
}

__global__ __launch_bounds__(256) void qkv_f32_kernel(
    const float* __restrict__ q, const float* __restrict__ k,
    const float* __restrict__ v, const float* __restrict__ wq,
    const float* __restrict__ wk, const float* __restrict__ wv,
    bf16* __restrict__ Q, bf16* __restrict__ K, bf16* __restrict__ Vt) {
  const int bid = blockIdx.x;
  const int xcd = bid & 7;
  const int j = bid >> 3;
  const int n = j & 7;
  const int rowslot = j >> 3;
  const int p = xcd * 12 + rowslot;
  const int z = p >> 5;
  const int y = p & 31;
  const float* A = (z == 0) ? q : (z == 1) ? k : v;
  const float* W = (z == 0) ? wq : (z == 1) ? wk : wv;
  bf16* C = (z == 0) ? Q : K;
  gemm_core<float, float, bf16>(A, W, (z == 2) ? nullptr : C,
                                (z == 2) ? Vt : nullptr, DMODEL, y * 128,
                                n * 128, (z == 0) ? CEXP : 1.0f);
}

__global__ __launch_bounds__(256) void oproj_f32_kernel(
    const bf16* __restrict__ A, const float* __restrict__ W,
    float* __restrict__ C) {
  const int bid = blockIdx.x;
  const int xcd = bid & 7;
  const int j = bid >> 3;
  const int n = j & 7;
  const int rowslot = j >> 3;
  const int y = xcd * 4 + rowslot;
  gemm_core<bf16, float, float>(A, W, C, nullptr, DMODEL, y * 128, n * 128,
                                1.0f);
}

// ---------------------------------------------------------------------------
// Causal flash attention v10: key-parity split -> 16 waves/CU at unchanged
// per-wave LDS amortization. 512 blocks x 512 threads (8 waves). Wave
// (kh=w&1, ws=w>>1): ws owns the same 16qL+16qH slice as v8's wave ws;
// the kh=0/1 twins split key tiles by parity (even/odd kt). Each super-iter
// stages a PAIR of 64-key K/V tiles; a wave reads only its parity tile
// (16 KB per 32 q -- amortization = v8) but waves/CU doubles 8 -> 16
// (v6-vs-v7 evidence: occupancy ~linear in this regime). Fixed-max softmax
// => partial O/l are purely additive; cross-parity combine is a one-time
// 40 KB LDS exchange. Barriers/block halve. LDS 64 KB, 2 blocks/CU,
// __launch_bounds__(512,4) caps VGPR at 128 (v8 measured 100).
// ---------------------------------------------------------------------------
// stage a pair of tiles (kt=2kb, 2kb+1) into parity slots 0/1. 8 waves x
// 4 x load_lds16: wave parity w&1 -> tile, sub w>>1 -> quarter.
__device__ __forceinline__ void stage_pair(const bf16* __restrict__ K,
                                           const bf16* __restrict__ Vt,
                                           bf16* Ksb, bf16* Vtsb, size_t baseQ,
                                           size_t baseV, int kb, int wave,
                                           int lane) {
  const int p = wave & 1;
  const int sub = wave >> 1;
  const int kt = 2 * kb + p;
  bf16* kd = Ksb + p * 4096;
  bf16* vd = Vtsb + p * 4096;
#pragma unroll
  for (int ii = 0; ii < 2; ++ii) {
    int i = sub * 2 + ii;
    int cb = i * 64;
    int c = cb + lane;
    int r = c >> 3;
    int s = (c & 7) ^ (r & 7);
    load_lds16(&K[baseQ + (size_t)(kt * 64 + r) * DMODEL + s * 8], &kd[cb * 8]);
    load_lds16(&Vt[baseV + (size_t)r * S_ + kt * 64 + s * 8], &vd[cb * 8]);
  }
}

template <bool DIAG>
__device__ __forceinline__ void softmax4(const floatx4 sa[4], bf16x4 pb[4],
                                         float lp[4], int quad, int qb) {
#pragma unroll
  for (int kg = 0; kg < 4; ++kg) {
    float pv[4];
#pragma unroll
    for (int r = 0; r < 4; ++r) {
      float s = sa[kg][r];
      if (DIAG) {
        int key = kg * 16 + quad * 4 + r;
        s = (key > qb) ? -3.0e38f : s;
      }
      float p = __builtin_amdgcn_exp2f(s);
      lp[kg] += p;
      pv[r] = p;
    }
    pb[kg] = bf16x4{(bf16)pv[0], (bf16)pv[1], (bf16)pv[2], (bf16)pv[3]};
  }
}

// single-tile step (H-only iterations and the H diagonal)
template <bool DIAG>
__device__ __forceinline__ void attn_tile(const bf16* Ks, const bf16* Vts,
                                          const bf16x8 qf[2], floatx4 ot[4],
                                          float lp[4], int quad, int l16,
                                          int qb) {
  floatx4 sa[4] = {};
#pragma unroll
  for (int kk = 0; kk < 2; ++kk)
#pragma unroll
    for (int kg = 0; kg < 4; ++kg) {
      bf16x8 ka = frag64(Ks, kg * 16 + l16, kk * 4 + quad);
      sa[kg] = MFMA16(ka, qf[kk], sa[kg]);
    }
  bf16x4 pb[4];
  softmax4<DIAG>(sa, pb, lp, quad, qb);
#pragma unroll
  for (int kg = 0; kg < 4; ++kg)
#pragma unroll
    for (int di = 0; di < 4; ++di) {
      bf16x4 va = frag64h(Vts, di * 16 + l16, kg * 2 + (quad >> 1), quad & 1);
      ot[di] = MFMAK16(va, pb[kg], ot[di]);
    }
}

// paired step: one ka/va load feeds both tiles. LMODE: 1=L full, 2=L diag.
template <int LMODE>
__device__ __forceinline__ void pair_tile(const bf16* Ks, const bf16* Vts,
                                          const bf16x8 qfL[2],
                                          const bf16x8 qfH[2], floatx4 otL[4],
                                          floatx4 otH[4], float lpL[4],
                                          float lpH[4], int quad, int l16,
                                          int qb) {
  floatx4 saL[4] = {}, saH[4] = {};
#pragma unroll
  for (int kk = 0; kk < 2; ++kk)
#pragma unroll
    for (int kg = 0; kg < 4; ++kg) {
      bf16x8 ka = frag64(Ks, kg * 16 + l16, kk * 4 + quad);
      saL[kg] = MFMA16(ka, qfL[kk], saL[kg]);
      saH[kg] = MFMA16(ka, qfH[kk], saH[kg]);
    }
  bf16x4 pbL[4], pbH[4];
  if (LMODE == 1)
    softmax4<false>(saL, pbL, lpL, quad, qb);
  else
    softmax4<true>(saL, pbL, lpL, quad, qb);
  softmax4<false>(saH, pbH, lpH, quad, qb);
#pragma unroll
  for (int kg = 0; kg < 4; ++kg)
#pragma unroll
    for (int di = 0; di < 4; ++di) {
      bf16x4 va = frag64h(Vts, di * 16 + l16, kg * 2 + (quad >> 1), quad & 1);
      otL[di] = MFMAK16(va, pbL[kg], otL[di]);
      otH[di] = MFMAK16(va, pbH[kg], otH[di]);
    }
}

__global__ __launch_bounds__(512, 4) void attn10_kernel(
    const bf16* __restrict__ Q, const bf16* __restrict__ K,
    const bf16* __restrict__ Vt, bf16* __restrict__ O) {
  __shared__ alignas(16) bf16 Ks[2][2 * 64 * 64];   // [dbuf][parity tile]
  __shared__ alignas(16) bf16 Vts[2][2 * 64 * 64];

  const int tid = threadIdx.x;
  const int wave = tid >> 6;
  const int lane = tid & 63;
  const int quad = lane >> 4;
  const int l16 = lane & 15;
  const int ws = wave >> 1;  // q-group slot (as v8's wave)
  const int kh = wave & 1;   // key parity

  const int j = blockIdx.x;
  const int bh = j & 31;   // bid&7 = bh&7: heads spread across XCDs, K/V L2-resident
  const int pr = j >> 5;   // 0..15: pair (pr, 31-pr) -> constant 33 units/block
  const int qtL = pr;
  const int qtH = 31 - pr;
  const int h = bh & 15;
  const int b = bh >> 4;
  const size_t baseQ = (size_t)b * S_ * DMODEL + (size_t)h * DKH;
  const size_t baseV = (size_t)bh * DKH * S_;

  // Q fragments in B-operand layout (lane=q, k=quad*8+j), pre-scaled by CEXP
  bf16x8 qfL[2], qfH[2];
#pragma unroll
  for (int kk = 0; kk < 2; ++kk) {
    qfL[kk] = *(const bf16x8*)&Q[baseQ +
        (size_t)(qtL * 64 + ws * 16 + l16) * DMODEL + kk * 32 + quad * 8];
    qfH[kk] = *(const bf16x8*)&Q[baseQ +
        (size_t)(qtH * 64 + ws * 16 + l16) * DMODEL + kk * 32 + quad * 8];
  }

  floatx4 otL[4] = {}, otH[4] = {};  // O^T partials (this parity's keys)
  float lpL[4] = {}, lpH[4] = {};    // l partials
  const int qb = ws * 16 + l16;      // q index within each 64-row tile

  const int NSI = (33 - pr) >> 1;    // ceil((qtH+1)/2) super-iterations

  stage_pair(K, Vt, Ks[0], Vts[0], baseQ, baseV, 0, wave, lane);
  __syncthreads();  // drains vmcnt(0)

  for (int kb = 0; kb < NSI; ++kb) {
    const int cur = kb & 1;
    if (kb + 1 < NSI)  // prefetch next pair; latency hides under compute
      stage_pair(K, Vt, Ks[cur ^ 1], Vts[cur ^ 1], baseQ, baseV, kb + 1, wave, lane);

    const int kt = 2 * kb + kh;
    __builtin_amdgcn_s_setprio(1);
    if (kt <= qtH) {
      const bf16* ks = Ks[cur] + kh * 4096;
      const bf16* vs = Vts[cur] + kh * 4096;
      if (kt < qtL)
        pair_tile<1>(ks, vs, qfL, qfH, otL, otH, lpL, lpH, quad, l16, qb);
      else if (kt == qtL)
        pair_tile<2>(ks, vs, qfL, qfH, otL, otH, lpL, lpH, quad, l16, qb);
      else if (kt == qtH)
        attn_tile<true>(ks, vs, qfH, otH, lpH, quad, l16, qb);
      else
        attn_tile<false>(ks, vs, qfH, otH, lpH, quad, l16, qb);
    }
    __builtin_amdgcn_s_setprio(0);

    __syncthreads();  // next buffer staged; this one free
  }

  // cross-parity combine: partial O/l are additive (fixed-max softmax).
  // kh=1 waves publish via LDS (reuse tile buffers), kh=0 waves merge+store.
  floatx4* ox = (floatx4*)&Ks[0][0];   // [ws][t][di][lane] : 32 KB
  float* lx = (float*)&Vts[0][0];      // [ws][t][kg][lane] : 8 KB
  if (kh == 1) {
#pragma unroll
    for (int di = 0; di < 4; ++di) {
      ox[((ws * 2 + 0) * 4 + di) * 64 + lane] = otL[di];
      ox[((ws * 2 + 1) * 4 + di) * 64 + lane] = otH[di];
    }
#pragma unroll
    for (int kg = 0; kg < 4; ++kg) {
      lx[((ws * 2 + 0) * 4 + kg) * 64 + lane] = lpL[kg];
      lx[((ws * 2 + 1) * 4 + kg) * 64 + lane] = lpH[kg];
    }
  }
  __syncthreads();
  if (kh == 0) {
#pragma unroll
    for (int di = 0; di < 4; ++di) {
      otL[di] += ox[((ws * 2 + 0) * 4 + di) * 64 + lane];
      otH[di] += ox[((ws * 2 + 1) * 4 + di) * 64 + lane];
    }
#pragma unroll
    for (int kg = 0; kg < 4; ++kg) {
      lpL[kg] += lx[((ws * 2 + 0) * 4 + kg) * 64 + lane];
      lpH[kg] += lx[((ws * 2 + 1) * 4 + kg) * 64 + lane];
    }

    // l: per-lane sum, reduce across the 4 quads sharing q=l16
    float lL = (lpL[0] + lpL[1]) + (lpL[2] + lpL[3]);
    lL += __shfl_xor(lL, 16, 64);
    lL += __shfl_xor(lL, 32, 64);
    float lH = (lpH[0] + lpH[1]) + (lpH[2] + lpH[3]);
    lH += __shfl_xor(lH, 16, 64);
    lH += __shfl_xor(lH, 32, 64);
    const float invL = 1.0f / lL;
    const float invH = 1.0f / lH;

    // store O^T -> O[q][d] (2B scattered; epilogue-only)
    const size_t orowL = baseQ + (size_t)(qtL * 64 + ws * 16 + l16) * DMODEL;
    const size_t orowH = baseQ + (size_t)(qtH * 64 + ws * 16 + l16) * DMODEL;
#pragma unroll
    for (int di = 0; di < 4; ++di)
#pragma unroll
      for (int r = 0; r < 4; ++r) {
        O[orowL + di * 16 + quad * 4 + r] = (bf16)(otL[di][r] * invL);
        O[orowH + di * 16 + quad * 4 + r] = (bf16)(otH[di][r] * invH);
      }
  }
}

// ---------------------------------------------------------------------------
extern "C" void kernel_launch(void* const* d_in, const int* in_sizes, int n_in,
                              void* d_out, int out_size, void* d_ws,
                              size_t ws_size, hipStream_t stream) {
  const float* q = (const float*)d_in[0];
  const float* k = (const float*)d_in[1];
  const float* v = (const float*)d_in[2];
  // d_in[3] = causal mask: static tril, computed analytically in-kernel
  const float* wq = (const float*)d_in[4];
  const float* wk = (const float*)d_in[5];
  const float* wv = (const float*)d_in[6];
  const float* wo = (const float*)d_in[7];
  float* out = (float*)d_out;

  const size_t MB = 1024 * 1024;
  char* base = (char*)d_ws;
  bf16* Qp = (bf16*)(base);
  bf16* Kp = (bf16*)(base + 8 * MB);
  bf16* VtG = (bf16*)(base + 16 * MB);
  bf16* AO = (bf16*)(base + 24 * MB);

  if (ws_size >= 64 * MB) {
    bf16* qb = (bf16*)(base + 32 * MB);
    bf16* kb = (bf16*)(base + 40 * MB);
    bf16* vb = (bf16*)(base + 48 * MB);
    bf16* wqb = (bf16*)(base + 56 * MB);
    bf16* wkb = (bf16*)(base + 58 * MB);
    bf16* wvb = (bf16*)(base + 60 * MB);
    bf16* wob = (bf16*)(base + 62 * MB);
    convert_kernel<<<dim3(2048, 7), 256, 0, stream>>>(
        q, k, v, wq, wk, wv, wo, qb, kb, vb, wqb, wkb, wvb, wob);
    qkv64_kernel<<<dim3(768), 256, 0, stream>>>(
        qb, kb, vb, wqb, wkb, wvb, Qp, Kp, VtG);
    attn10_kernel<<<dim3(512), 512, 0, stream>>>(Qp, Kp, VtG, AO);
    oproj64_kernel<<<dim3(512), 256, 0, stream>>>(AO, wob, out);
  } else {
    qkv_f32_kernel<<<dim3(768), 256, 0, stream>>>(
        q, k, v, wq, wk, wv, Qp, Kp, VtG);
    attn10_kernel<<<dim3(512), 512, 0, stream>>>(Qp, Kp, VtG, AO);
    oproj_f32_kernel<<<dim3(256), 256, 0, stream>>>(AO, wo, out);
  }
}